// Round 3
// baseline (837.810 us; speedup 1.0000x reference)
//
#include <hip/hip_runtime.h>

typedef unsigned short u16;
typedef __bf16 v8bf __attribute__((ext_vector_type(8)));
typedef float v4f __attribute__((ext_vector_type(4)));
typedef u16 v8u16 __attribute__((ext_vector_type(8)));

// ---------------- geometry constants ----------------
// X (input): [512][18][18][18*18] fp32, plane (z,w) = 324 contiguous
#define X_B 104976   // 18*18*324
#define X_A 5832     // 18*324
#define X_P 324
// Xb (bf16, padded plane 324->328 for 16B alignment of plane bases)
#define XB_B 106272  // 18*18*328
#define XB_A 5904    // 18*328
#define XB_P 328
#define XB_ELEMS 54411328u   // 512*106272 + 64 tail pad
// GEMM: M=18432 (b,x,y), N=112 (108 used: o*36+zo*6+wo), K'=169*352=59488
#define KP 59488
#define SLAB 352
#define NPAD 112
#define B2_ELEMS 6662656u    // 112*59488
#define C_ELEMS 2064384u     // 18432*112
#define KSPLIT 11
#define NBLK (72 * KSPLIT)
// ws layout (bytes)
#define WS_C   0
#define WS_B2  8257536ull
#define WS_XB  21582848ull
#define WS_FAST_NEED 130405504ull

__device__ __forceinline__ u16 f2bf(float f) {
    unsigned u = __builtin_bit_cast(unsigned, f);
    u += 0x7fffu + ((u >> 16) & 1u);   // RNE
    return (u16)(u >> 16);
}

#define AS1C(p) (const __attribute__((address_space(1))) void*)(p)
#define AS3(p)  (__attribute__((address_space(3))) void*)(p)
// wait vmcnt(0) only: lgkmcnt=15 (no wait) [11:8], expcnt=7 (no wait) [6:4]
#define WAIT_VM0 0x0F70

// ---------------- prep: x fp32 -> padded bf16 (vectorized: v8u16 stores) ----
__global__ void conv_bf16_kernel(const float* __restrict__ X, u16* __restrict__ Xb) {
    const int bx = blockIdx.x;             // 0..9215 = 512*18
    const long xbbase = (long)bx * XB_A;
    const long xfbase = (long)bx * X_A;
    for (int s = threadIdx.x; s < 738; s += 256) {
        int y = s / 41;                    // 328/8 = 41 slots per plane row
        int pos = (s - y * 41) * 8;        // 0..320, multiple of 8
        const float* src = X + xfbase + y * 324 + pos;
        float4 lo = *(const float4*)src;                       // pos+3 <= 323 always
        float4 hi = (pos + 4 < 324) ? *(const float4*)(src + 4)
                                    : make_float4(0.f, 0.f, 0.f, 0.f);
        v8u16 p;
        p[0] = f2bf(lo.x); p[1] = f2bf(lo.y); p[2] = f2bf(lo.z); p[3] = f2bf(lo.w);
        p[4] = f2bf(hi.x); p[5] = f2bf(hi.y); p[6] = f2bf(hi.z); p[7] = f2bf(hi.w);
        *(v8u16*)(Xb + xbbase + s * 8) = p;
    }
}

// ---------------- prep: Toeplitz weight B2[n][k'] bf16 (v8 stores), + zero C
__global__ void build_b2_kernel(const float* __restrict__ W, u16* __restrict__ B2,
                                float* __restrict__ C) {
    unsigned t = blockIdx.x * 256u + threadIdx.x;
    if (t < 516096u) ((float4*)C)[t] = make_float4(0.f, 0.f, 0.f, 0.f);
    if (t >= 832832u) return;              // B2_ELEMS/8
    unsigned n = t / 7436u;                // KP/8
    unsigned k0 = (t - n * 7436u) * 8u;
    unsigned slab = k0 / 352u;
    unsigned jj0 = k0 - slab * 352u;       // multiple of 8
    v8u16 out = {0, 0, 0, 0, 0, 0, 0, 0};
    if (n < 108u && jj0 < 324u) {
        unsigned kx = slab / 13u, ky = slab - kx * 13u;
        unsigned o = n / 36u, zw = n - o * 36u;
        unsigned zo = zw / 6u, wo = zw - zo * 6u;
        const float* wb = W + o * 28561u + kx * 2197u + ky * 169u;
#pragma unroll
        for (int e = 0; e < 8; ++e) {
            unsigned jj = jj0 + e;
            if (jj < 324u) {
                unsigned jz = jj / 18u, jw = jj - jz * 18u;
                int dz = (int)jz - (int)zo, dw = (int)jw - (int)wo;
                if (dz >= 0 && dz < 13 && dw >= 0 && dw < 13)
                    out[e] = f2bf(wb[dz * 13 + dw]);
            }
        }
    }
    ((v8u16*)B2)[t] = out;
}

// ---------------- main GEMM: C[(b,x,y)][(o,zo,wo)] += A·B2 ----------------
// grid = 72 m-tiles x 11 k-splits = 792 blocks (~3 resident/CU, LDS 46 KB).
// Pipelined 2-buffer: issue loads(s+1) right after the barrier opening step s.
// XOR swizzle on chunk index kills the 64B-row-stride bank conflicts.
template<bool USE_XB>
__global__ __launch_bounds__(256, 3) void gemm_conv(
    const u16* __restrict__ Xb, const float* __restrict__ Xf,
    const u16* __restrict__ B2, float* __restrict__ C)
{
    __shared__ u16 Alds[2][256 * 32];   // [m 0..255][k 0..31], swizzled chunks
    __shared__ u16 Blds[2][112 * 32];   // [n 0..111][k 0..31], swizzled chunks

    const int tid = threadIdx.x;
    const int lane = tid & 63;
    const int wv = tid >> 6;
    const int mt = blockIdx.x % 72;
    const int ks = blockIdx.x / 72;

    const int sbeg = (ks * 169) / KSPLIT;
    const int send = ((ks + 1) * 169) / KSPLIT;
    const int nsteps = (send - sbeg) * 11;   // 11 K32-steps per 352-slab

    int laneA[4], chunkA[4];
#pragma unroll
    for (int jr = 0; jr < 4; ++jr) {
        int slot = jr * 256 + tid;
        int row = slot >> 2;
        int chunk = (slot & 3) ^ ((slot >> 3) & 3);
        int r = mt * 256 + row;
        int b = r / 36;
        int xy = r - b * 36;
        int x = xy / 6;
        int y = xy - x * 6;
        if (USE_XB) laneA[jr] = b * XB_B + x * XB_A + y * XB_P + chunk * 8;
        else        laneA[jr] = b * X_B + x * X_A + y * X_P;
        chunkA[jr] = chunk;
    }
    const int chunkB = (tid & 3) ^ ((tid >> 3) & 3);
    const int laneB0 = (tid >> 2) * KP + chunkB * 8;      // slots 0..255
    const int laneB1 = laneB0 + 64 * KP;                  // slots 256..447 (wv<3)

    v4f acc[4][7];
#pragma unroll
    for (int i = 0; i < 4; ++i)
#pragma unroll
        for (int t = 0; t < 7; ++t) acc[i][t] = (v4f){0.f, 0.f, 0.f, 0.f};

    auto stage = [&](int step, int p) {
        int q = step / 11;
        int si = step - q * 11;
        int slab = sbeg + q;
        int kx = slab / 13;
        int ky = slab - kx * 13;
        if (USE_XB) {
            int aofs = kx * XB_A + ky * XB_P + si * 32;
#pragma unroll
            for (int jr = 0; jr < 4; ++jr) {
                const u16* gp = Xb + (laneA[jr] + aofs);
                __builtin_amdgcn_global_load_lds(AS1C(gp), AS3(&Alds[p][(jr * 256 + wv * 64) * 8]), 16, 0, 0);
            }
        } else {
            int aofs = kx * X_A + ky * X_P;
#pragma unroll
            for (int jr = 0; jr < 4; ++jr) {
                int jj0 = si * 32 + chunkA[jr] * 8;
                const float* gp = Xf + (laneA[jr] + aofs);
                float4 lo = make_float4(0.f, 0.f, 0.f, 0.f);
                float4 hi = make_float4(0.f, 0.f, 0.f, 0.f);
                if (jj0 < 324)     lo = *(const float4*)(gp + jj0);
                if (jj0 + 4 < 324) hi = *(const float4*)(gp + jj0 + 4);
                v8u16 pk;
                pk[0] = f2bf(lo.x); pk[1] = f2bf(lo.y); pk[2] = f2bf(lo.z); pk[3] = f2bf(lo.w);
                pk[4] = f2bf(hi.x); pk[5] = f2bf(hi.y); pk[6] = f2bf(hi.z); pk[7] = f2bf(hi.w);
                int slot = jr * 256 + tid;
                *(v8u16*)(&Alds[p][slot * 8]) = pk;
            }
        }
        int bofs = slab * SLAB + si * 32;
        const u16* gp0 = B2 + (laneB0 + bofs);
        __builtin_amdgcn_global_load_lds(AS1C(gp0), AS3(&Blds[p][(wv * 64) * 8]), 16, 0, 0);
        if (wv < 3) {
            const u16* gp1 = B2 + (laneB1 + bofs);
            __builtin_amdgcn_global_load_lds(AS1C(gp1), AS3(&Blds[p][(256 + wv * 64) * 8]), 16, 0, 0);
        }
    };

    stage(0, 0);

    for (int step = 0; step < nsteps; ++step) {
        const int p = step & 1;
        __builtin_amdgcn_s_waitcnt(WAIT_VM0);  // my buf-p loads landed
        __builtin_amdgcn_s_barrier();          // everyone's landed; p^1 reads done
        if (step + 1 < nsteps) stage(step + 1, p ^ 1);   // fly during compute

        v8bf a[4];
#pragma unroll
        for (int i = 0; i < 4; ++i) {
            int row = wv * 64 + i * 16 + (lane & 15);
            int slot = row * 4 + ((lane >> 4) ^ ((row >> 1) & 3));
            a[i] = *(const v8bf*)(&Alds[p][slot * 8]);
        }
#pragma unroll
        for (int t = 0; t < 7; ++t) {
            int row = t * 16 + (lane & 15);
            int slot = row * 4 + ((lane >> 4) ^ ((row >> 1) & 3));
            v8bf bb = *(const v8bf*)(&Blds[p][slot * 8]);
#pragma unroll
            for (int i = 0; i < 4; ++i)
                acc[i][t] = __builtin_amdgcn_mfma_f32_16x16x32_bf16(a[i], bb, acc[i][t], 0, 0, 0);
        }
    }

    // ---- split-K accumulate into C ----
    const int colb = lane & 15;
    const int rq = (lane >> 4) * 4;
#pragma unroll
    for (int i = 0; i < 4; ++i) {
        int rowb = mt * 256 + wv * 64 + i * 16 + rq;
#pragma unroll
        for (int t = 0; t < 7; ++t) {
            int col = t * 16 + colb;
#pragma unroll
            for (int g = 0; g < 4; ++g)
                atomicAdd(&C[(rowb + g) * NPAD + col], acc[i][t][g]);
        }
    }
}

// ---------------- fused bias+ReLU+linear+sigmoid ----------------
__global__ void epilogue_kernel(const float* __restrict__ C, const float* __restrict__ cb,
                                const float* __restrict__ lw, const float* __restrict__ lb,
                                float* __restrict__ out) {
    const int b = blockIdx.x;
    const int tid = threadIdx.x;
    float s = 0.f;
    for (int t = tid; t < 3888; t += 256) {
        int xy = t / 108, n = t - xy * 108;
        int o = n / 36, zw = n - o * 36;
        int x = xy / 6, y = xy - x * 6;
        float c = C[(b * 36 + xy) * NPAD + n] + cb[o];
        s += fmaxf(c, 0.f) * lw[o * 1296 + x * 216 + y * 36 + zw];
    }
#pragma unroll
    for (int off = 32; off > 0; off >>= 1) s += __shfl_down(s, off, 64);
    __shared__ float red[4];
    if ((tid & 63) == 0) red[tid >> 6] = s;
    __syncthreads();
    if (tid == 0)
        out[b] = 1.f / (1.f + expf(-(red[0] + red[1] + red[2] + red[3] + lb[0])));
}

extern "C" void kernel_launch(void* const* d_in, const int* in_sizes, int n_in,
                              void* d_out, int out_size, void* d_ws, size_t ws_size,
                              hipStream_t stream) {
    const float* X  = (const float*)d_in[0];
    const float* W  = (const float*)d_in[1];
    const float* cb = (const float*)d_in[2];
    const float* lw = (const float*)d_in[3];
    const float* lb = (const float*)d_in[4];
    float* out = (float*)d_out;
    char* ws = (char*)d_ws;
    float* C  = (float*)(ws + WS_C);
    u16* B2   = (u16*)(ws + WS_B2);
    u16* Xb   = (u16*)(ws + WS_XB);
    const bool fast = ws_size >= WS_FAST_NEED;

    build_b2_kernel<<<3254, 256, 0, stream>>>(W, B2, C);
    if (fast) {
        conv_bf16_kernel<<<9216, 256, 0, stream>>>(X, Xb);
        gemm_conv<true><<<NBLK, 256, 0, stream>>>(Xb, X, B2, C);
    } else {
        gemm_conv<false><<<NBLK, 256, 0, stream>>>(nullptr, X, B2, C);
    }
    epilogue_kernel<<<512, 256, 0, stream>>>(C, cb, lw, lb, out);
}

// Round 4
// 718.700 us; speedup vs baseline: 1.1657x; 1.1657x over previous
//
#include <hip/hip_runtime.h>

typedef unsigned short u16;
typedef __bf16 v8bf __attribute__((ext_vector_type(8)));
typedef float v4f __attribute__((ext_vector_type(4)));
typedef u16 v8u16 __attribute__((ext_vector_type(8)));

// ---------------- geometry constants ----------------
// X (input): [512][18][18][18*18] fp32, plane (z,w) = 324 contiguous
#define X_B 104976   // 18*18*324
#define X_A 5832     // 18*324
#define X_P 324
// Xb (bf16, padded plane 324->328 for 16B alignment of plane bases)
#define XB_B 106272  // 18*18*328
#define XB_A 5904    // 18*328
#define XB_P 328
#define XB_ELEMS 54411328u   // 512*106272 + 64 tail pad
// GEMM: M=18432 (b,x,y), N=112 (108 used: o*36+zo*6+wo), K'=169*352=59488
#define KP 59488
#define SLAB 352
#define NPAD 112
#define B2_ELEMS 6662656u    // 112*59488
#define C_ELEMS 2064384u     // 18432*112
#define KSPLIT 7
#define NBLK (72 * KSPLIT)
// ws layout (bytes)
#define WS_C   0
#define WS_B2  8257536ull
#define WS_XB  21582848ull
#define WS_FAST_NEED 130405504ull

__device__ __forceinline__ u16 f2bf(float f) {
    unsigned u = __builtin_bit_cast(unsigned, f);
    u += 0x7fffu + ((u >> 16) & 1u);   // RNE
    return (u16)(u >> 16);
}

#define AS1C(p) (const __attribute__((address_space(1))) void*)(p)
#define AS3(p)  (__attribute__((address_space(3))) void*)(p)
// s_waitcnt imm: vmcnt[3:0], expcnt[6:4]=7 (no wait), lgkmcnt[11:8]=15 (no wait)
#define WAIT_VM3 0x0F73
#define WAIT_VM0 0x0F70

// ---------------- prep: x fp32 -> padded bf16 (vectorized: v8u16 stores) ----
__global__ void conv_bf16_kernel(const float* __restrict__ X, u16* __restrict__ Xb) {
    const int bx = blockIdx.x;             // 0..9215 = 512*18
    const long xbbase = (long)bx * XB_A;
    const long xfbase = (long)bx * X_A;
    for (int s = threadIdx.x; s < 738; s += 256) {
        int y = s / 41;                    // 328/8 = 41 slots per plane row
        int pos = (s - y * 41) * 8;        // 0..320, multiple of 8
        const float* src = X + xfbase + y * 324 + pos;
        float4 lo = *(const float4*)src;                       // pos+3 <= 323 always
        float4 hi = (pos + 4 < 324) ? *(const float4*)(src + 4)
                                    : make_float4(0.f, 0.f, 0.f, 0.f);
        v8u16 p;
        p[0] = f2bf(lo.x); p[1] = f2bf(lo.y); p[2] = f2bf(lo.z); p[3] = f2bf(lo.w);
        p[4] = f2bf(hi.x); p[5] = f2bf(hi.y); p[6] = f2bf(hi.z); p[7] = f2bf(hi.w);
        *(v8u16*)(Xb + xbbase + s * 8) = p;
    }
}

// ---------------- prep: Toeplitz weight B2[n][k'] bf16 (v8 stores), + zero C
__global__ void build_b2_kernel(const float* __restrict__ W, u16* __restrict__ B2,
                                float* __restrict__ C) {
    unsigned t = blockIdx.x * 256u + threadIdx.x;
    if (t < 516096u) ((float4*)C)[t] = make_float4(0.f, 0.f, 0.f, 0.f);
    if (t >= 832832u) return;              // B2_ELEMS/8
    unsigned n = t / 7436u;                // KP/8
    unsigned k0 = (t - n * 7436u) * 8u;
    unsigned slab = k0 / 352u;
    unsigned jj0 = k0 - slab * 352u;       // multiple of 8
    v8u16 out = {0, 0, 0, 0, 0, 0, 0, 0};
    if (n < 108u && jj0 < 324u) {
        unsigned kx = slab / 13u, ky = slab - kx * 13u;
        unsigned o = n / 36u, zw = n - o * 36u;
        unsigned zo = zw / 6u, wo = zw - zo * 6u;
        const float* wb = W + o * 28561u + kx * 2197u + ky * 169u;
#pragma unroll
        for (int e = 0; e < 8; ++e) {
            unsigned jj = jj0 + e;
            if (jj < 324u) {
                unsigned jz = jj / 18u, jw = jj - jz * 18u;
                int dz = (int)jz - (int)zo, dw = (int)jw - (int)wo;
                if (dz >= 0 && dz < 13 && dw >= 0 && dw < 13)
                    out[e] = f2bf(wb[dz * 13 + dw]);
            }
        }
    }
    ((v8u16*)B2)[t] = out;
}

// ---------------- main GEMM: C[(b,x,y)][(o,zo,wo)] += A·B2 ----------------
// 504 blocks x 512 threads (8 waves): 16 waves/CU at 2 blocks/CU.
// Triple-buffered LDS, prefetch distance 2, per-step wait vmcnt(3) (every
// thread issues exactly 3 global_load_lds per stage: 2 A + 1 B; wave 7
// idempotently duplicates wave 6's B slots to keep counts uniform).
// XOR swizzle on chunk index keeps LDS conflict-free (verified 0 in R2/R3).
template<bool USE_XB>
__global__ __launch_bounds__(512, 4) void gemm_conv(
    const u16* __restrict__ Xb, const float* __restrict__ Xf,
    const u16* __restrict__ B2, float* __restrict__ C)
{
    __shared__ u16 Alds[3][256 * 32];   // [m 0..255][k 0..31], swizzled chunks
    __shared__ u16 Blds[3][112 * 32];   // [n 0..111][k 0..31], swizzled chunks

    const int tid = threadIdx.x;
    const int lane = tid & 63;
    const int wv = tid >> 6;            // 0..7
    const int bwv = (wv < 7) ? wv : 6;  // wave 7 duplicates wave 6's B load
    const int mt = blockIdx.x % 72;
    const int ks = blockIdx.x / 72;

    const int sbeg = (ks * 169) / KSPLIT;
    const int send = ((ks + 1) * 169) / KSPLIT;
    const int nsteps = (send - sbeg) * 11;   // 11 K32-steps per 352-slab

    int laneA[2], chunkA[2];
#pragma unroll
    for (int jr = 0; jr < 2; ++jr) {
        int slot = jr * 512 + tid;
        int row = slot >> 2;
        int chunk = (slot & 3) ^ ((slot >> 3) & 3);
        int r = mt * 256 + row;
        int b = r / 36;
        int xy = r - b * 36;
        int x = xy / 6;
        int y = xy - x * 6;
        if (USE_XB) laneA[jr] = b * XB_B + x * XB_A + y * XB_P + chunk * 8;
        else        laneA[jr] = b * X_B + x * X_A + y * X_P;
        chunkA[jr] = chunk;
    }
    const int bslot = bwv * 64 + lane;
    const int chunkB = (bslot & 3) ^ ((bslot >> 3) & 3);
    const int laneB = (bslot >> 2) * KP + chunkB * 8;

    v4f acc[2][7];
#pragma unroll
    for (int i = 0; i < 2; ++i)
#pragma unroll
        for (int t = 0; t < 7; ++t) acc[i][t] = (v4f){0.f, 0.f, 0.f, 0.f};

    auto stage = [&](int step, int p) {
        int q = step / 11;
        int si = step - q * 11;
        int slab = sbeg + q;
        int kx = slab / 13;
        int ky = slab - kx * 13;
        if (USE_XB) {
            int aofs = kx * XB_A + ky * XB_P + si * 32;
#pragma unroll
            for (int jr = 0; jr < 2; ++jr) {
                const u16* gp = Xb + (laneA[jr] + aofs);
                __builtin_amdgcn_global_load_lds(AS1C(gp), AS3(&Alds[p][(jr * 512 + wv * 64) * 8]), 16, 0, 0);
            }
        } else {
            int aofs = kx * X_A + ky * X_P;
#pragma unroll
            for (int jr = 0; jr < 2; ++jr) {
                int jj0 = si * 32 + chunkA[jr] * 8;
                const float* gp = Xf + (laneA[jr] + aofs);
                float4 lo = make_float4(0.f, 0.f, 0.f, 0.f);
                float4 hi = make_float4(0.f, 0.f, 0.f, 0.f);
                if (jj0 < 324)     lo = *(const float4*)(gp + jj0);
                if (jj0 + 4 < 324) hi = *(const float4*)(gp + jj0 + 4);
                v8u16 pk;
                pk[0] = f2bf(lo.x); pk[1] = f2bf(lo.y); pk[2] = f2bf(lo.z); pk[3] = f2bf(lo.w);
                pk[4] = f2bf(hi.x); pk[5] = f2bf(hi.y); pk[6] = f2bf(hi.z); pk[7] = f2bf(hi.w);
                int slot = jr * 512 + tid;
                *(v8u16*)(&Alds[p][slot * 8]) = pk;
            }
        }
        int bofs = slab * SLAB + si * 32;
        const u16* gp0 = B2 + (laneB + bofs);
        __builtin_amdgcn_global_load_lds(AS1C(gp0), AS3(&Blds[p][(bwv * 64) * 8]), 16, 0, 0);
    };

    stage(0, 0);
    stage(1, 1);

    for (int step = 0; step < nsteps; ++step) {
        const int p = step % 3;
        if (USE_XB) {
            if (step + 1 < nsteps) __builtin_amdgcn_s_waitcnt(WAIT_VM3);  // keep s+1 in flight
            else                   __builtin_amdgcn_s_waitcnt(WAIT_VM0);  // final drain
        } else {
            __builtin_amdgcn_s_waitcnt(0);
        }
        __builtin_amdgcn_s_barrier();          // buf p complete; step s-1 readers done
        if (step + 2 < nsteps) stage(step + 2, (step + 2) % 3);

        v8bf a[2];
#pragma unroll
        for (int i = 0; i < 2; ++i) {
            int row = wv * 32 + i * 16 + (lane & 15);
            int slot = row * 4 + ((lane >> 4) ^ ((row >> 1) & 3));
            a[i] = *(const v8bf*)(&Alds[p][slot * 8]);
        }
#pragma unroll
        for (int t = 0; t < 7; ++t) {
            int row = t * 16 + (lane & 15);
            int slot = row * 4 + ((lane >> 4) ^ ((row >> 1) & 3));
            v8bf bb = *(const v8bf*)(&Blds[p][slot * 8]);
#pragma unroll
            for (int i = 0; i < 2; ++i)
                acc[i][t] = __builtin_amdgcn_mfma_f32_16x16x32_bf16(a[i], bb, acc[i][t], 0, 0, 0);
        }
    }

    // ---- split-K accumulate into C ----
    const int colb = lane & 15;
    const int rq = (lane >> 4) * 4;
#pragma unroll
    for (int i = 0; i < 2; ++i) {
        int rowb = mt * 256 + wv * 32 + i * 16 + rq;
#pragma unroll
        for (int t = 0; t < 7; ++t) {
            int col = t * 16 + colb;
#pragma unroll
            for (int g = 0; g < 4; ++g)
                atomicAdd(&C[(rowb + g) * NPAD + col], acc[i][t][g]);
        }
    }
}

// ---------------- fused bias+ReLU+linear+sigmoid ----------------
__global__ void epilogue_kernel(const float* __restrict__ C, const float* __restrict__ cb,
                                const float* __restrict__ lw, const float* __restrict__ lb,
                                float* __restrict__ out) {
    const int b = blockIdx.x;
    const int tid = threadIdx.x;
    float s = 0.f;
    for (int t = tid; t < 3888; t += 256) {
        int xy = t / 108, n = t - xy * 108;
        int o = n / 36, zw = n - o * 36;
        int x = xy / 6, y = xy - x * 6;
        float c = C[(b * 36 + xy) * NPAD + n] + cb[o];
        s += fmaxf(c, 0.f) * lw[o * 1296 + x * 216 + y * 36 + zw];
    }
#pragma unroll
    for (int off = 32; off > 0; off >>= 1) s += __shfl_down(s, off, 64);
    __shared__ float red[4];
    if ((tid & 63) == 0) red[tid >> 6] = s;
    __syncthreads();
    if (tid == 0)
        out[b] = 1.f / (1.f + expf(-(red[0] + red[1] + red[2] + red[3] + lb[0])));
}

extern "C" void kernel_launch(void* const* d_in, const int* in_sizes, int n_in,
                              void* d_out, int out_size, void* d_ws, size_t ws_size,
                              hipStream_t stream) {
    const float* X  = (const float*)d_in[0];
    const float* W  = (const float*)d_in[1];
    const float* cb = (const float*)d_in[2];
    const float* lw = (const float*)d_in[3];
    const float* lb = (const float*)d_in[4];
    float* out = (float*)d_out;
    char* ws = (char*)d_ws;
    float* C  = (float*)(ws + WS_C);
    u16* B2   = (u16*)(ws + WS_B2);
    u16* Xb   = (u16*)(ws + WS_XB);
    const bool fast = ws_size >= WS_FAST_NEED;

    build_b2_kernel<<<3254, 256, 0, stream>>>(W, B2, C);
    if (fast) {
        conv_bf16_kernel<<<9216, 256, 0, stream>>>(X, Xb);
        gemm_conv<true><<<NBLK, 512, 0, stream>>>(Xb, X, B2, C);
    } else {
        gemm_conv<false><<<NBLK, 512, 0, stream>>>(nullptr, X, B2, C);
    }
    epilogue_kernel<<<512, 256, 0, stream>>>(C, cb, lw, lb, out);
}